// Round 2
// baseline (242.653 us; speedup 1.0000x reference)
//
#include <hip/hip_runtime.h>

// CtaPostAttnMixer: y = (I + 0.1*Lap)^4 x along l, boundaries l=0, L-1 fixed.
// Composed into one 9-tap convolution (interior) + analytic boundary rows.
// x: (B=4, L=8192, D=1024) f32, D contiguous. One thread = one float4 d-quad.
//
// R1 lesson: SEG=64 -> 2 waves/SIMD, latency-bound 2.5 TB/s.
// R3 lesson: C=16 FULL 24-row window (96 VGPR) -> compiler serialized loads
//   into dependent batches; BW stuck at 2.7 TB/s.
// R4 lesson: XCD swizzle neutral. Counters: hbm_bytes=201MB @ 80us = 2.5TB/s
//   (NOT HBM-bound), VALUBusy 7%, occ 77%. But RAW demand (3x halo amp at
//   C=4) = 402MB read + 134MB write = 536MB / 80us = 6.7 TB/s = the fabric
//   ceiling. Cache-hit traffic above L2 is not materially cheaper than HBM.
//   => reduce DEMAND, not placement.
// R5 (this round): C=16 via rolling 3-bank register window. Banks A/B/C of
//   4 rows rotate roles across 4 statically-unrolled phases -> no register
//   moves, live window stays 12 rows (48 VGPR), next-phase loads issue into
//   the bank that just went dead. Read amp 3x -> 1.5x: demand 320MB -> ~48us.
//   Blocks 8192 -> 2048 (also tests the CP-dispatch-rate hypothesis).

namespace {

constexpr int Lr   = 8192;          // sequence length
constexpr int Dq   = 1024 / 4;      // float4 columns = 256
constexpr int Bn   = 4;             // batch
constexpr int C    = 16;            // rows per thread (4 phases of 4)
constexpr int SEGS = Lr / C;        // 512
constexpr int NXCD = 8;             // MI355X chiplets
constexpr int NWG  = SEGS * Bn;     // 2048 blocks, % NXCD == 0 -> bijective

// standard 9-tap weights of (I + a*Lap)^4, a = 0.1 (exact: p=[.1,.8,.1]^*4)
constexpr float WK0 = 0.4870f;
constexpr float WK1 = 0.2144f;
constexpr float WK2 = 0.0388f;
constexpr float WK3 = 0.0032f;
constexpr float WK4 = 0.0001f;

typedef float nfloat4 __attribute__((ext_vector_type(4)));  // native vec4

__device__ __forceinline__ float4 f4_add(float4 a, float4 b) {
    return make_float4(a.x + b.x, a.y + b.y, a.z + b.z, a.w + b.w);
}
__device__ __forceinline__ float4 f4_mul(float s, float4 a) {
    return make_float4(s * a.x, s * a.y, s * a.z, s * a.w);
}
__device__ __forceinline__ float4 f4_fma(float s, float4 a, float4 c) {
    return make_float4(fmaf(s, a.x, c.x), fmaf(s, a.y, c.y),
                       fmaf(s, a.z, c.z), fmaf(s, a.w, c.w));
}
__device__ __forceinline__ void f4_store_nt(float4* p, float4 v) {
    nfloat4 nv;
    nv.x = v.x; nv.y = v.y; nv.z = v.z; nv.w = v.w;
    __builtin_nontemporal_store(nv, (nfloat4*)p);
}

// Interior phase: write rows r0..r0+3; window w[i] = x[r0-4+i], i=0..11,
// supplied as three 4-row banks P,Q,R. The w[] copies are SSA-renamed away.
__device__ __forceinline__ void interior_phase(
        float4* __restrict__ yb, int r0,
        const float4 (&P)[4], const float4 (&Q)[4], const float4 (&R)[4]) {
    float4 w[12];
#pragma unroll
    for (int i = 0; i < 4; ++i) { w[i] = P[i]; w[i + 4] = Q[i]; w[i + 8] = R[i]; }
#pragma unroll
    for (int j = 0; j < 4; ++j) {
        float4 acc = f4_mul(WK0, w[j + 4]);
        acc = f4_fma(WK1, f4_add(w[j + 3], w[j + 5]), acc);
        acc = f4_fma(WK2, f4_add(w[j + 2], w[j + 6]), acc);
        acc = f4_fma(WK3, f4_add(w[j + 1], w[j + 7]), acc);
        acc = f4_fma(WK4, f4_add(w[j + 0], w[j + 8]), acc);
        f4_store_nt(&yb[(size_t)(r0 + j) * Dq], acc);
    }
}

// Boundary rows l=0..3. Q = x[0..3], R = x[4..7].
__device__ __forceinline__ void boundary_low(
        float4* __restrict__ yb, const float4 (&Q)[4], const float4 (&R)[4]) {
    // l=0: copy
    f4_store_nt(&yb[0], Q[0]);
    // l=1
    {
        float4 o = f4_mul(0.2986f, Q[0]);
        o = f4_fma(0.4482f, Q[1], o);
        o = f4_fma(0.2112f, Q[2], o);
        o = f4_fma(0.0387f, Q[3], o);
        o = f4_fma(0.0032f, R[0], o);
        o = f4_fma(0.0001f, R[1], o);
        f4_store_nt(&yb[(size_t)1 * Dq], o);
    }
    // l=2
    {
        float4 o = f4_mul(0.0454f, Q[0]);
        o = f4_fma(0.2112f, Q[1], o);
        o = f4_fma(0.4869f, Q[2], o);
        o = f4_fma(0.2144f, Q[3], o);
        o = f4_fma(0.0388f, R[0], o);
        o = f4_fma(0.0032f, R[1], o);
        o = f4_fma(0.0001f, R[2], o);
        f4_store_nt(&yb[(size_t)2 * Dq], o);
    }
    // l=3
    {
        float4 o = f4_mul(0.0034f, Q[0]);
        o = f4_fma(0.0387f, Q[1], o);
        o = f4_fma(0.2144f, Q[2], o);
        o = f4_fma(0.4870f, Q[3], o);
        o = f4_fma(0.2144f, R[0], o);
        o = f4_fma(0.0388f, R[1], o);
        o = f4_fma(0.0032f, R[2], o);
        o = f4_fma(0.0001f, R[3], o);
        f4_store_nt(&yb[(size_t)3 * Dq], o);
    }
}

// Boundary rows l=L-4..L-1 (mirrored). P = x[L-8..L-5], Q = x[L-4..L-1].
// In the old w[] naming: w[i]=P[i] (i<4), w[4+i]=Q[i].
__device__ __forceinline__ void boundary_high(
        float4* __restrict__ yb, const float4 (&P)[4], const float4 (&Q)[4]) {
    // l = L-1: copy
    f4_store_nt(&yb[(size_t)(Lr - 1) * Dq], Q[3]);
    // l = L-2: mirrored row1
    {
        float4 o = f4_mul(0.2986f, Q[3]);
        o = f4_fma(0.4482f, Q[2], o);
        o = f4_fma(0.2112f, Q[1], o);
        o = f4_fma(0.0387f, Q[0], o);
        o = f4_fma(0.0032f, P[3], o);
        o = f4_fma(0.0001f, P[2], o);
        f4_store_nt(&yb[(size_t)(Lr - 2) * Dq], o);
    }
    // l = L-3: mirrored row2
    {
        float4 o = f4_mul(0.0454f, Q[3]);
        o = f4_fma(0.2112f, Q[2], o);
        o = f4_fma(0.4869f, Q[1], o);
        o = f4_fma(0.2144f, Q[0], o);
        o = f4_fma(0.0388f, P[3], o);
        o = f4_fma(0.0032f, P[2], o);
        o = f4_fma(0.0001f, P[1], o);
        f4_store_nt(&yb[(size_t)(Lr - 3) * Dq], o);
    }
    // l = L-4: mirrored row3
    {
        float4 o = f4_mul(0.0034f, Q[3]);
        o = f4_fma(0.0387f, Q[2], o);
        o = f4_fma(0.2144f, Q[1], o);
        o = f4_fma(0.4870f, Q[0], o);
        o = f4_fma(0.2144f, P[3], o);
        o = f4_fma(0.0388f, P[2], o);
        o = f4_fma(0.0032f, P[1], o);
        o = f4_fma(0.0001f, P[0], o);
        f4_store_nt(&yb[(size_t)(Lr - 4) * Dq], o);
    }
}

__global__ __launch_bounds__(256, 6)   // cap VGPR ~85 -> >=24 waves/CU
void mixer4_kernel(const float4* __restrict__ x, float4* __restrict__ y) {
    const int d4  = threadIdx.x;        // 0..255  (float4 column)

    // XCD-aware bijective swizzle (NWG % 8 == 0): XCD k owns contiguous
    // work ids [k*256, (k+1)*256) -> halo rows shared between neighboring
    // segs stay in the same XCD's L2.
    const int lin = blockIdx.x;                       // 0..NWG-1
    const int g   = (lin & (NXCD - 1)) * (NWG / NXCD) + (lin >> 3);
    const int b   = g >> 9;                           // g / SEGS (SEGS=512)
    const int seg = g & (SEGS - 1);                   // g % SEGS
    const int c0  = seg * C;

    const float4* __restrict__ xb = x + (size_t)b * Lr * Dq + d4;
    float4* __restrict__       yb = y + (size_t)b * Lr * Dq + d4;

    auto ld = [&](int row) -> float4 {
        row = row < 0 ? 0 : row;
        row = row > Lr - 1 ? Lr - 1 : row;
        return xb[(size_t)row * Dq];
    };

    // Rolling 3-bank window: banks of 4 rows rotate through the 12-row
    // window across 4 statically-unrolled phases. No register moves.
    float4 A[4], B[4], Cb[4];
#pragma unroll
    for (int i = 0; i < 4; ++i) A[i]  = ld(c0 - 4 + i);   // rows c0-4..c0-1
#pragma unroll
    for (int i = 0; i < 4; ++i) B[i]  = ld(c0 + i);       // rows c0..c0+3
#pragma unroll
    for (int i = 0; i < 4; ++i) Cb[i] = ld(c0 + 4 + i);   // rows c0+4..c0+7

    // phase 0: window A|B|Cb -> rows c0..c0+3 ; refill A <- rows c0+8..11
    if (seg != 0) {
        interior_phase(yb, c0, A, B, Cb);
    } else {
        boundary_low(yb, B, Cb);   // B = x[0..3], Cb = x[4..7]
    }
#pragma unroll
    for (int i = 0; i < 4; ++i) A[i] = ld(c0 + 8 + i);

    // phase 1: window B|Cb|A -> rows c0+4..7 ; refill B <- rows c0+12..15
    interior_phase(yb, c0 + 4, B, Cb, A);
#pragma unroll
    for (int i = 0; i < 4; ++i) B[i] = ld(c0 + 12 + i);

    // phase 2: window Cb|A|B -> rows c0+8..11 ; refill Cb <- rows c0+16..19
    interior_phase(yb, c0 + 8, Cb, A, B);
#pragma unroll
    for (int i = 0; i < 4; ++i) Cb[i] = ld(c0 + 16 + i);  // clamped dups at last seg (unused)

    // phase 3: window A|B|Cb -> rows c0+12..15
    if (seg != SEGS - 1) {
        interior_phase(yb, c0 + 12, A, B, Cb);
    } else {
        boundary_high(yb, A, B);   // A = x[L-8..L-5], B = x[L-4..L-1]
    }
}

}  // namespace

extern "C" void kernel_launch(void* const* d_in, const int* in_sizes, int n_in,
                              void* d_out, int out_size, void* d_ws, size_t ws_size,
                              hipStream_t stream) {
    const float4* x = (const float4*)d_in[0];
    float4*       y = (float4*)d_out;

    dim3 grid(NWG);        // 2048 blocks, 1D so the swizzle owns the mapping
    dim3 block(256);       // 256 threads = full D (256 float4 columns)
    hipLaunchKernelGGL(mixer4_kernel, grid, block, 0, stream, x, y);
}

// Round 3
// 237.271 us; speedup vs baseline: 1.0227x; 1.0227x over previous
//
#include <hip/hip_runtime.h>

// CtaPostAttnMixer: y = (I + 0.1*Lap)^4 x along l, boundaries l=0, L-1 fixed.
// Composed into one 9-tap convolution (interior) + analytic boundary rows.
// x: (B=4, L=8192, D=1024) f32, D contiguous. One thread = one float4 d-quad
// over a 4-row l-chunk (12-row raw window incl. 4-row halo each side).
//
// R1 lesson: SEG=64 -> 2 waves/SIMD, latency-bound 2.5 TB/s.
// R3 lesson: C=16 full window (96 VGPR) -> compiler serialized loads.
// R4 lesson: XCD swizzle neutral; hbm_bytes 201MB @ 2.5 TB/s, VALU 7%.
// R5 lesson: C=16 rolling banks: demand 536->335MB yet time 80->89us.
//   Invariant found: dur == hbm_bytes / 2.5 TB/s in BOTH R4+R5. And
//   VGPR_Count=36 < the 48 the bank window needs => compiler serialized
//   the loads AGAIN (register-minimizing heuristic), so every variant so
//   far ran dependent 3-4-deep load chains -> latency wall at 2.5 TB/s.
// R6 (this round): back to C=4 / 8192 blocks (best TLP: 77% occ), but
//   FORCE all 12 window float4s live via an empty asm keep-alive between
//   loads and compute -> compiler must emit 12 independent loads, one
//   waitcnt, 12 KB/wave in flight (the m13-copy pattern that hits 6.3
//   TB/s). Also drop nontemporal stores (fill hits 6.7 TB/s with plain
//   stores; nt bypasses L2/L3 for no measured gain).
//   Verify: VGPR_Count must jump 32 -> ~60. Predict mixer 80 -> ~50us.

namespace {

constexpr int Lr   = 8192;          // sequence length
constexpr int Dq   = 1024 / 4;      // float4 columns = 256
constexpr int Bn   = 4;             // batch
constexpr int C    = 4;             // chunk length along l (= per-thread span)
constexpr int W    = C + 8;         // raw window rows = 12
constexpr int SEGS = Lr / C;        // 2048
constexpr int NXCD = 8;             // MI355X chiplets
constexpr int NWG  = SEGS * Bn;     // 8192 blocks, % NXCD == 0 -> bijective

// standard 9-tap weights of (I + a*Lap)^4, a = 0.1 (exact: p=[.1,.8,.1]^*4)
constexpr float WK0 = 0.4870f;
constexpr float WK1 = 0.2144f;
constexpr float WK2 = 0.0388f;
constexpr float WK3 = 0.0032f;
constexpr float WK4 = 0.0001f;

__device__ __forceinline__ float4 f4_add(float4 a, float4 b) {
    return make_float4(a.x + b.x, a.y + b.y, a.z + b.z, a.w + b.w);
}
__device__ __forceinline__ float4 f4_mul(float s, float4 a) {
    return make_float4(s * a.x, s * a.y, s * a.z, s * a.w);
}
__device__ __forceinline__ float4 f4_fma(float s, float4 a, float4 c) {
    return make_float4(fmaf(s, a.x, c.x), fmaf(s, a.y, c.y),
                       fmaf(s, a.z, c.z), fmaf(s, a.w, c.w));
}

__global__ __launch_bounds__(256, 8)   // pin VGPR<=64 -> 32 waves/CU
void mixer4_kernel(const float4* __restrict__ x, float4* __restrict__ y) {
    const int d4  = threadIdx.x;        // 0..255  (float4 column)

    // XCD-aware bijective swizzle (NWG % 8 == 0): XCD k owns contiguous
    // work ids -> halo re-reads between neighboring segs stay in one L2.
    const int lin = blockIdx.x;                       // 0..NWG-1
    const int g   = (lin & (NXCD - 1)) * (NWG / NXCD) + (lin >> 3);
    const int b   = g >> 11;                          // g / SEGS  (SEGS=2048)
    const int seg = g & (SEGS - 1);                   // g % SEGS
    const int c0  = seg * C;

    const float4* __restrict__ xb = x + (size_t)b * Lr * Dq + d4;
    float4* __restrict__       yb = y + (size_t)b * Lr * Dq + d4;

    // raw input window: w[i] = x[clamp(c0 - 4 + i)], 12 loads
    float4 w[W];
#pragma unroll
    for (int i = 0; i < W; ++i) {
        int gl = c0 - 4 + i;
        gl = gl < 0 ? 0 : gl;
        gl = gl > Lr - 1 ? Lr - 1 : gl;
        w[i] = xb[(size_t)gl * Dq];
    }
    // Force ALL 12 float4s (48 VGPR) live here: compiler must issue the 12
    // loads independently (back-to-back, single waitcnt) instead of
    // register-minimizing into dependent serialized batches (R3/R5 defect).
#pragma unroll
    for (int i = 0; i < W; ++i) {
        asm volatile("" : "+v"(w[i].x), "+v"(w[i].y), "+v"(w[i].z), "+v"(w[i].w));
    }

    if (c0 != 0 && c0 != Lr - C) {
        // interior: standard 9-tap conv for the 4 outputs
#pragma unroll
        for (int j = 0; j < C; ++j) {
            float4 acc = f4_mul(WK0, w[j + 4]);
            acc = f4_fma(WK1, f4_add(w[j + 3], w[j + 5]), acc);
            acc = f4_fma(WK2, f4_add(w[j + 2], w[j + 6]), acc);
            acc = f4_fma(WK3, f4_add(w[j + 1], w[j + 7]), acc);
            acc = f4_fma(WK4, f4_add(w[j + 0], w[j + 8]), acc);
            yb[(size_t)(c0 + j) * Dq] = acc;
        }
    } else if (c0 == 0) {
        // chunk 0: rows l=0..3 are ALL boundary-special. w[4+i] = x[i].
        yb[0] = w[4];   // l=0: copy
        // l=1
        {
            float4 o = f4_mul(0.2986f, w[4]);
            o = f4_fma(0.4482f, w[5], o);
            o = f4_fma(0.2112f, w[6], o);
            o = f4_fma(0.0387f, w[7], o);
            o = f4_fma(0.0032f, w[8], o);
            o = f4_fma(0.0001f, w[9], o);
            yb[(size_t)1 * Dq] = o;
        }
        // l=2
        {
            float4 o = f4_mul(0.0454f, w[4]);
            o = f4_fma(0.2112f, w[5], o);
            o = f4_fma(0.4869f, w[6], o);
            o = f4_fma(0.2144f, w[7], o);
            o = f4_fma(0.0388f, w[8], o);
            o = f4_fma(0.0032f, w[9], o);
            o = f4_fma(0.0001f, w[10], o);
            yb[(size_t)2 * Dq] = o;
        }
        // l=3
        {
            float4 o = f4_mul(0.0034f, w[4]);
            o = f4_fma(0.0387f, w[5], o);
            o = f4_fma(0.2144f, w[6], o);
            o = f4_fma(0.4870f, w[7], o);
            o = f4_fma(0.2144f, w[8], o);
            o = f4_fma(0.0388f, w[9], o);
            o = f4_fma(0.0032f, w[10], o);
            o = f4_fma(0.0001f, w[11], o);
            yb[(size_t)3 * Dq] = o;
        }
    } else {
        // last chunk: rows l=L-4..L-1 all special (mirrored).
        // w[i] = x[Lr-8+i] for i=0..7 (i>=8 clamped dups). x[Lr-1-p] = w[7-p].
        yb[(size_t)(Lr - 1) * Dq] = w[7];   // l = L-1: copy
        // l = L-2: mirrored row1
        {
            float4 o = f4_mul(0.2986f, w[7]);
            o = f4_fma(0.4482f, w[6], o);
            o = f4_fma(0.2112f, w[5], o);
            o = f4_fma(0.0387f, w[4], o);
            o = f4_fma(0.0032f, w[3], o);
            o = f4_fma(0.0001f, w[2], o);
            yb[(size_t)(Lr - 2) * Dq] = o;
        }
        // l = L-3: mirrored row2
        {
            float4 o = f4_mul(0.0454f, w[7]);
            o = f4_fma(0.2112f, w[6], o);
            o = f4_fma(0.4869f, w[5], o);
            o = f4_fma(0.2144f, w[4], o);
            o = f4_fma(0.0388f, w[3], o);
            o = f4_fma(0.0032f, w[2], o);
            o = f4_fma(0.0001f, w[1], o);
            yb[(size_t)(Lr - 3) * Dq] = o;
        }
        // l = L-4: mirrored row3
        {
            float4 o = f4_mul(0.0034f, w[7]);
            o = f4_fma(0.0387f, w[6], o);
            o = f4_fma(0.2144f, w[5], o);
            o = f4_fma(0.4870f, w[4], o);
            o = f4_fma(0.2144f, w[3], o);
            o = f4_fma(0.0388f, w[2], o);
            o = f4_fma(0.0032f, w[1], o);
            o = f4_fma(0.0001f, w[0], o);
            yb[(size_t)(Lr - 4) * Dq] = o;
        }
    }
}

}  // namespace

extern "C" void kernel_launch(void* const* d_in, const int* in_sizes, int n_in,
                              void* d_out, int out_size, void* d_ws, size_t ws_size,
                              hipStream_t stream) {
    const float4* x = (const float4*)d_in[0];
    float4*       y = (float4*)d_out;

    dim3 grid(NWG);        // 8192 blocks, 1D so the swizzle owns the mapping
    dim3 block(256);       // 256 threads = full D (256 float4 columns)
    hipLaunchKernelGGL(mixer4_kernel, grid, block, 0, stream, x, y);
}

// Round 4
// 228.069 us; speedup vs baseline: 1.0639x; 1.0403x over previous
//
#include <hip/hip_runtime.h>

// CtaPostAttnMixer: y = (I + 0.1*Lap)^4 x along l, boundaries l=0, L-1 fixed.
// One 9-tap convolution (interior) + analytic boundary rows.
// x: (B=4, L=8192, D=1024) f32, D contiguous.
//
// R1: SEG=64 -> 2 waves/SIMD, latency-bound 2.5 TB/s.
// R3/R5/R6: EVERY register-held multi-row window gets serialized by the
//   register allocator (VGPR_Count 28-36 < window size; asm keep-alive
//   ineffective). Dependent load chains -> latency wall.
// R4/R6 counters: demand (loads+stores incl. cache hits) = 536 MB at
//   80us = 6.7 TB/s = the m13 copy ceiling (~10 B/cy/CU). The kernel is
//   DEMAND-bound: 3x halo read amplification at C=4 makes it move 536 MB
//   of vector-memory traffic for 256 MB of useful data. Cache hits are
//   not cheaper than misses on this path.
// R7 (this round): hold the window in LDS, not registers. Block stages a
//   40-row x 64-float4 strip (40 KB) with global_load_lds (direct-to-LDS
//   DMA: no VGPR round trip -> the allocator CANNOT serialize it), then
//   computes 32 rows. Amp 3x -> 1.25x: demand 288 MB -> predict ~50us.
//   4 blocks/CU (4 x 40KB = 160KB LDS), 16 waves/CU, 160KB loads in
//   flight per CU. Staging + LDS reads are contiguous -> conflict-free.

namespace {

constexpr int Lr   = 8192;           // sequence length
constexpr int Dq   = 1024 / 4;       // float4 columns = 256
constexpr int Bn   = 4;              // batch
constexpr int R    = 32;             // output rows per block
constexpr int WR   = R + 8;          // staged rows (4-halo each side) = 40
constexpr int CW   = 64;             // float4 columns per block (1 KB rows)
constexpr int RT   = Lr / R;         // 256 row tiles
constexpr int CT   = Dq / CW;        // 4 col tiles
constexpr int NXCD = 8;              // MI355X chiplets
constexpr int NWG  = RT * CT * Bn;   // 4096 blocks, % NXCD == 0 -> bijective

// standard 9-tap weights of (I + a*Lap)^4, a = 0.1 (exact: p=[.1,.8,.1]^*4)
constexpr float WK0 = 0.4870f;
constexpr float WK1 = 0.2144f;
constexpr float WK2 = 0.0388f;
constexpr float WK3 = 0.0032f;
constexpr float WK4 = 0.0001f;

__device__ __forceinline__ float4 f4_add(float4 a, float4 b) {
    return make_float4(a.x + b.x, a.y + b.y, a.z + b.z, a.w + b.w);
}
__device__ __forceinline__ float4 f4_mul(float s, float4 a) {
    return make_float4(s * a.x, s * a.y, s * a.z, s * a.w);
}
__device__ __forceinline__ float4 f4_fma(float s, float4 a, float4 c) {
    return make_float4(fmaf(s, a.x, c.x), fmaf(s, a.y, c.y),
                       fmaf(s, a.z, c.z), fmaf(s, a.w, c.w));
}

__global__ __launch_bounds__(256, 4)   // 4 blocks/CU (LDS-limited anyway), VGPR<=128
void mixer4_kernel(const float4* __restrict__ x, float4* __restrict__ y) {
    __shared__ float4 tile[WR][CW];    // 40 KB, rows contiguous (1 KB stride)

    // XCD-aware bijective swizzle: XCD k owns contiguous work ids ->
    // consecutive row-tiles (which share 8 halo rows) stay in one L2.
    const int lin = blockIdx.x;                        // 0..NWG-1
    const int g   = (lin & (NXCD - 1)) * (NWG / NXCD) + (lin >> 3);
    const int rt  = g & (RT - 1);                      // row tile, fastest
    const int bc  = g >> 8;                            // (b, coltile) group
    const int ct  = bc & (CT - 1);
    const int b   = bc >> 2;
    const int r0  = rt * R;

    const size_t origin = (size_t)b * Lr * Dq + (size_t)ct * CW;
    const float4* __restrict__ xt = x + origin;        // tile origin (row 0)
    float4* __restrict__       yt = y + origin;

    const int lane = threadIdx.x & 63;                 // column within strip
    const int wid  = threadIdx.x >> 6;                 // wave 0..3

    // ---- stage WR rows, one 1 KB global_load_lds issue per row ----------
    // LDS dest is wave-uniform base + lane*16 (HW constraint) -> row i goes
    // to &tile[i][0], lanes supply consecutive 16B global sources. DMA has
    // no VGPR destination -> cannot be serialized by the allocator.
#pragma unroll
    for (int ii = 0; ii < WR / 4; ++ii) {
        const int i  = wid + ii * 4;                   // 0..39, each exactly once
        int grow = r0 - 4 + i;
        grow = grow < 0 ? 0 : grow;
        grow = grow > Lr - 1 ? Lr - 1 : grow;
        const float4* src = xt + (size_t)grow * Dq + lane;
        __builtin_amdgcn_global_load_lds(
            (const __attribute__((address_space(1))) void*)src,
            (__attribute__((address_space(3))) void*)&tile[i][0],
            16, 0, 0);
    }
    __syncthreads();   // compiler drains vmcnt before s_barrier

    // ---- compute: wave w -> local output rows w*8 .. w*8+7 ---------------
    // Output local row k needs LDS rows k..k+8; this wave needs kbase..kbase+15.
    const int kbase = wid * 8;
    float4 win[16];
#pragma unroll
    for (int i = 0; i < 16; ++i) win[i] = tile[kbase + i][lane];

    auto interior = [&](int j) {       // j constant after full unroll
        float4 acc = f4_mul(WK0, win[j + 4]);
        acc = f4_fma(WK1, f4_add(win[j + 3], win[j + 5]), acc);
        acc = f4_fma(WK2, f4_add(win[j + 2], win[j + 6]), acc);
        acc = f4_fma(WK3, f4_add(win[j + 1], win[j + 7]), acc);
        acc = f4_fma(WK4, f4_add(win[j + 0], win[j + 8]), acc);
        yt[(size_t)(r0 + kbase + j) * Dq + lane] = acc;
    };

    const bool low  = (r0 == 0)       && (wid == 0);   // global rows 0..7
    const bool high = (r0 == Lr - R)  && (wid == 3);   // global rows L-8..L-1

    if (low) {
        // win[4+m] = x[m] (rows -4..-1 staged as clamped dups of x[0])
        yt[0 * (size_t)Dq + lane] = win[4];            // l=0: copy
        {   // l=1
            float4 o = f4_mul(0.2986f, win[4]);
            o = f4_fma(0.4482f, win[5], o);
            o = f4_fma(0.2112f, win[6], o);
            o = f4_fma(0.0387f, win[7], o);
            o = f4_fma(0.0032f, win[8], o);
            o = f4_fma(0.0001f, win[9], o);
            yt[1 * (size_t)Dq + lane] = o;
        }
        {   // l=2
            float4 o = f4_mul(0.0454f, win[4]);
            o = f4_fma(0.2112f, win[5], o);
            o = f4_fma(0.4869f, win[6], o);
            o = f4_fma(0.2144f, win[7], o);
            o = f4_fma(0.0388f, win[8], o);
            o = f4_fma(0.0032f, win[9], o);
            o = f4_fma(0.0001f, win[10], o);
            yt[2 * (size_t)Dq + lane] = o;
        }
        {   // l=3
            float4 o = f4_mul(0.0034f, win[4]);
            o = f4_fma(0.0387f, win[5], o);
            o = f4_fma(0.2144f, win[6], o);
            o = f4_fma(0.4870f, win[7], o);
            o = f4_fma(0.2144f, win[8], o);
            o = f4_fma(0.0388f, win[9], o);
            o = f4_fma(0.0032f, win[10], o);
            o = f4_fma(0.0001f, win[11], o);
            yt[3 * (size_t)Dq + lane] = o;
        }
#pragma unroll
        for (int j = 4; j < 8; ++j) interior(j);       // rows 4..7 standard
    } else if (high) {
#pragma unroll
        for (int j = 0; j < 4; ++j) interior(j);       // rows L-8..L-5 standard
        // win[4+m] = x[L-8+m]: P = win[4..7], Q = win[8..11]
        yt[(size_t)(Lr - 1) * Dq + lane] = win[11];    // l=L-1: copy
        {   // l=L-2 (mirrored row1)
            float4 o = f4_mul(0.2986f, win[11]);
            o = f4_fma(0.4482f, win[10], o);
            o = f4_fma(0.2112f, win[9], o);
            o = f4_fma(0.0387f, win[8], o);
            o = f4_fma(0.0032f, win[7], o);
            o = f4_fma(0.0001f, win[6], o);
            yt[(size_t)(Lr - 2) * Dq + lane] = o;
        }
        {   // l=L-3 (mirrored row2)
            float4 o = f4_mul(0.0454f, win[11]);
            o = f4_fma(0.2112f, win[10], o);
            o = f4_fma(0.4869f, win[9], o);
            o = f4_fma(0.2144f, win[8], o);
            o = f4_fma(0.0388f, win[7], o);
            o = f4_fma(0.0032f, win[6], o);
            o = f4_fma(0.0001f, win[5], o);
            yt[(size_t)(Lr - 3) * Dq + lane] = o;
        }
        {   // l=L-4 (mirrored row3)
            float4 o = f4_mul(0.0034f, win[11]);
            o = f4_fma(0.0387f, win[10], o);
            o = f4_fma(0.2144f, win[9], o);
            o = f4_fma(0.4870f, win[8], o);
            o = f4_fma(0.2144f, win[7], o);
            o = f4_fma(0.0388f, win[6], o);
            o = f4_fma(0.0032f, win[5], o);
            o = f4_fma(0.0001f, win[4], o);
            yt[(size_t)(Lr - 4) * Dq + lane] = o;
        }
    } else {
#pragma unroll
        for (int j = 0; j < 8; ++j) interior(j);
    }
}

}  // namespace

extern "C" void kernel_launch(void* const* d_in, const int* in_sizes, int n_in,
                              void* d_out, int out_size, void* d_ws, size_t ws_size,
                              hipStream_t stream) {
    const float4* x = (const float4*)d_in[0];
    float4*       y = (float4*)d_out;

    dim3 grid(NWG);        // 4096 blocks, 1D so the swizzle owns the mapping
    dim3 block(256);
    hipLaunchKernelGGL(mixer4_kernel, grid, block, 0, stream, x, y);
}